// Round 4
// baseline (58.213 us; speedup 1.0000x reference)
//
#include <hip/hip_runtime.h>

// Problem constants (from reference)
#define TOK_CODE_START 256
#define TOK_CODE_END   257
#define TOK_MEM        258
#define ADDR_KEY       206
#define MEM_STORE      455

constexpr int Bb = 16;
constexpr int Ss = 8192;
constexpr int DM = 512;
constexpr int POS_PER_BLK = 64;           // positions handled per block
constexpr int QPP = DM / 4;               // 128 float4 quads per position
constexpr int THREADS = 256;

typedef float f32x4 __attribute__((ext_vector_type(4)));

// ---------------------------------------------------------------------------
// Single fused kernel. Block bk owns row b = bk>>7, positions [s0, s0+64),
// output quads [bk*8192, bk*8192+8192).
//
// Phase 1 (mask): redundantly reduce token prefix [0, s0) to
//   P = latest CODE_START index, E = earliest CODE_END index
// (a block never needs tokens after its own range: idx < end_idx  <=>
//  min END over [0..idx] > idx). Wave 0 then shuffle-scans the block's own
// 64 tokens and writes one packed mask word per position to LDS:
//   bits[0..8]=token  bit9=valid  bit10=mem_flag  bits[11..]=addr
//
// Phase 2 (stream): gather embed quads (L2-resident) + apply mask +
// nontemporal coalesced float4 stores.
// ---------------------------------------------------------------------------
__global__ __launch_bounds__(THREADS) void vm_fused_kernel(
    const int* __restrict__ tok,
    const f32x4* __restrict__ emb,
    const int* __restrict__ mhe_p,
    f32x4* __restrict__ out)
{
    const int bk = blockIdx.x;            // 0..2047
    const int b  = bk >> 7;               // 128 chunks per row
    const int c  = bk & 127;
    const int t  = threadIdx.x;
    const int lane = t & 63;
    const int wid  = t >> 6;              // 0..3
    const int s0 = c * POS_PER_BLK;
    const int* row = tok + b * Ss;
    const int mhe = mhe_p[0];

    __shared__ int sP[4], sE[4];
    __shared__ unsigned int smask[POS_PER_BLK];

    // own-token prefetch (used by wave 0 after the barrier)
    int myTok = 0;
    if (t < POS_PER_BLK) myTok = row[s0 + t];

    // ---- prefix reduce over [0, s0): 32 tokens per thread via int4 ----
    int maxStart = -1;
    int minEnd = Ss;
    {
        const int base = t * 32;
        if (base < s0) {                  // s0 mult of 64, base mult of 32 -> full chunk
            #pragma unroll
            for (int j = 0; j < 8; ++j) {
                int4 v = reinterpret_cast<const int4*>(row + base + j * 4)[0];
                int i0 = base + j * 4;
                if (v.x == TOK_CODE_START) maxStart = i0;
                if (v.y == TOK_CODE_START) maxStart = i0 + 1;
                if (v.z == TOK_CODE_START) maxStart = i0 + 2;
                if (v.w == TOK_CODE_START) maxStart = i0 + 3;     // ascending -> max
                if (v.x == TOK_CODE_END && minEnd == Ss) minEnd = i0;
                if (v.y == TOK_CODE_END && minEnd == Ss) minEnd = i0 + 1;
                if (v.z == TOK_CODE_END && minEnd == Ss) minEnd = i0 + 2;
                if (v.w == TOK_CODE_END && minEnd == Ss) minEnd = i0 + 3;
            }
        }
    }
    // wave reduce (max / min)
    #pragma unroll
    for (int off = 32; off > 0; off >>= 1) {
        int u = __shfl_xor(maxStart, off);
        if (u > maxStart) maxStart = u;
        int w = __shfl_xor(minEnd, off);
        if (w < minEnd) minEnd = w;
    }
    if (lane == 0) { sP[wid] = maxStart; sE[wid] = minEnd; }
    __syncthreads();

    // ---- wave 0: finish scan for own 64 positions ----
    if (t < POS_PER_BLK) {
        int P = max(max(sP[0], sP[1]), max(sP[2], sP[3]));
        int E = min(min(sE[0], sE[1]), min(sE[2], sE[3]));

        const int idx = s0 + t;
        int st = (myTok == TOK_CODE_START) ? idx : -1;
        int en = (myTok == TOK_CODE_END) ? idx : Ss;
        // inclusive max-scan (st) and min-scan (en) over 64 lanes
        #pragma unroll
        for (int off = 1; off < 64; off <<= 1) {
            int u = __shfl_up(st, off);
            int v = __shfl_up(en, off);
            if (lane >= off) {
                if (u > st) st = u;
                if (v < en) en = v;
            }
        }
        int cs = max(P, st);                       // latest start at-or-before idx
        int firstEnd = min(E, en);                 // earliest end at-or-before idx (or Ss)
        int addr = idx - cs - 1;
        bool valid = (cs >= 0) && (firstEnd > idx) && (myTok < 256) && (addr >= 0);
        bool memf  = (myTok == TOK_MEM) && (idx < mhe);
        unsigned int w = (unsigned int)myTok;      // bits 0..8
        if (valid) w |= (1u << 9) | ((unsigned int)addr << 11);
        if (memf)  w |= (1u << 10);
        smask[t] = w;
    }
    __syncthreads();

    // ---- phase 2: gather + mask + stream out ----
    const int outBase = bk * (POS_PER_BLK * QPP);  // bk * 8192
    #pragma unroll 8
    for (int i = 0; i < 32; ++i) {
        int q = i * THREADS + t;                   // 0..8191, coalesced
        int pos = q >> 7;
        int dq = q & 127;
        unsigned int pw = smask[pos];
        int tk = (int)(pw & 511u);
        f32x4 v = emb[tk * QPP + dq];
        unsigned int flags = pw >> 9;
        if (flags) {                               // ~wave-uniform, mostly false
            bool valid = (flags & 1u) != 0u;
            bool memf  = (flags & 2u) != 0u;
            int addr = (int)(flags >> 2);
            int p0 = ADDR_KEY      + (addr & 15);
            int p1 = ADDR_KEY + 16 + ((addr >> 4) & 15);
            int p2 = ADDR_KEY + 32 + ((addr >> 8) & 15);
            int d0 = dq << 2;
            #pragma unroll
            for (int j = 0; j < 4; ++j) {
                int d = d0 + j;
                if ((valid && (d == p0 || d == p1 || d == p2)) ||
                    (memf && d == MEM_STORE)) v[j] = 1.0f;
            }
        }
        __builtin_nontemporal_store(v, &out[outBase + q]);
    }
}

extern "C" void kernel_launch(void* const* d_in, const int* in_sizes, int n_in,
                              void* d_out, int out_size, void* d_ws, size_t ws_size,
                              hipStream_t stream) {
    const int* tok = (const int*)d_in[0];
    const f32x4* emb = (const f32x4*)d_in[1];
    const int* mhe = (const int*)d_in[2];
    f32x4* out = (f32x4*)d_out;

    vm_fused_kernel<<<Bb * (Ss / POS_PER_BLK), THREADS, 0, stream>>>(tok, emb, mhe, out);
}

// Round 5
// 53.612 us; speedup vs baseline: 1.0858x; 1.0858x over previous
//
#include <hip/hip_runtime.h>

// Problem constants (from reference)
#define TOK_CODE_START 256
#define TOK_CODE_END   257
#define TOK_MEM        258
#define ADDR_KEY       206
#define MEM_STORE      455

constexpr int Bb = 16;
constexpr int Ss = 8192;
constexpr int DM = 512;
constexpr int CHUNK = 64;            // positions per gather block
constexpr int NCH = Ss / CHUNK;      // 128 chunks per row
constexpr int QPP = DM / 4;          // 128 float4 quads per position

typedef float f32x4 __attribute__((ext_vector_type(4)));

// ---------------------------------------------------------------------------
// Kernel 1 (tiny): per-row chunk summaries + exclusive prefix scan.
// One block per row, 128 threads; thread t reduces chunk t's 64 tokens to
// {last CODE_START idx, first CODE_END idx}, then a 2-wave exclusive scan
// produces, per chunk: P = latest START strictly before the chunk (-1 none),
// E = earliest END strictly before the chunk (Ss none). 16 KB output.
// ---------------------------------------------------------------------------
__global__ __launch_bounds__(128) void vm_summary_kernel(
    const int* __restrict__ tok,
    int2* __restrict__ summ)
{
    const int b = blockIdx.x;
    const int t = threadIdx.x;           // chunk id 0..127
    const int lane = t & 63;
    const int w = t >> 6;                // 0 or 1
    const int* chunk = tok + b * Ss + t * CHUNK;

    int maxStart = -1, minEnd = Ss;
    #pragma unroll
    for (int j = 0; j < 16; ++j) {
        int4 v = reinterpret_cast<const int4*>(chunk)[j];
        int i0 = t * CHUNK + j * 4;
        if (v.x == TOK_CODE_START) maxStart = i0;
        if (v.y == TOK_CODE_START) maxStart = i0 + 1;
        if (v.z == TOK_CODE_START) maxStart = i0 + 2;
        if (v.w == TOK_CODE_START) maxStart = i0 + 3;     // ascending -> max
        if (v.x == TOK_CODE_END && minEnd == Ss) minEnd = i0;
        if (v.y == TOK_CODE_END && minEnd == Ss) minEnd = i0 + 1;
        if (v.z == TOK_CODE_END && minEnd == Ss) minEnd = i0 + 2;
        if (v.w == TOK_CODE_END && minEnd == Ss) minEnd = i0 + 3;
    }

    // inclusive wave scans (max of maxStart, min of minEnd)
    int ms = maxStart, me = minEnd;
    #pragma unroll
    for (int off = 1; off < 64; off <<= 1) {
        int u = __shfl_up(ms, off);
        int v = __shfl_up(me, off);
        if (lane >= off) { if (u > ms) ms = u; if (v < me) me = v; }
    }
    __shared__ int cMs, cMe;             // wave-0 totals (carry into wave 1)
    if (w == 0 && lane == 63) { cMs = ms; cMe = me; }
    __syncthreads();
    // exclusive = shift by one, identity at lane 0, carry for wave 1
    int pms = __shfl_up(ms, 1);
    int pme = __shfl_up(me, 1);
    if (lane == 0) { pms = -1; pme = Ss; }
    if (w == 1) { if (cMs > pms) pms = cMs; if (cMe < pme) pme = cMe; }
    summ[b * NCH + t] = make_int2(pms, pme);
}

// ---------------------------------------------------------------------------
// Kernel 2: gather + mask + stream. Block bk owns row b=bk>>7, chunk c=bk&127.
// Wave 0 finishes the scan for its own 64 positions (coalesced 64-token load
// + chunk-prefix pair + 6 shuffle steps) -> packed mask words in LDS:
//   bits[0..8]=token  bit9=valid  bit10=mem_flag  bits[11..]=addr
// All waves then stream: L2-resident embed gather + mask + regular
// (through-L2) dwordx4 stores, matching the fill kernel's proven path.
// ---------------------------------------------------------------------------
__global__ __launch_bounds__(256) void vm_gather_kernel(
    const int* __restrict__ tok,
    const f32x4* __restrict__ emb,
    const int2* __restrict__ summ,
    const int* __restrict__ mhe_p,
    f32x4* __restrict__ out)
{
    const int bk = blockIdx.x;            // 0..2047
    const int b  = bk >> 7;
    const int c  = bk & 127;
    const int t  = threadIdx.x;
    const int lane = t & 63;
    const int s0 = c * CHUNK;

    __shared__ unsigned int smask[CHUNK];

    if (t < 64) {
        const int idx = s0 + lane;
        int tv = tok[b * Ss + idx];
        int2 pe = summ[bk];               // == summ[b*NCH + c]
        int st = (tv == TOK_CODE_START) ? idx : -1;
        int en = (tv == TOK_CODE_END) ? idx : Ss;
        #pragma unroll
        for (int off = 1; off < 64; off <<= 1) {
            int u = __shfl_up(st, off);
            int v = __shfl_up(en, off);
            if (lane >= off) { if (u > st) st = u; if (v < en) en = v; }
        }
        int cs = max(pe.x, st);           // latest START at-or-before idx
        int fe = min(pe.y, en);           // earliest END at-or-before idx (Ss if none)
        int addr = idx - cs - 1;
        bool valid = (cs >= 0) && (fe > idx) && (tv < 256) && (addr >= 0);
        bool memf  = (tv == TOK_MEM) && (idx < mhe_p[0]);
        unsigned int wd = (unsigned int)tv;              // bits 0..8
        if (valid) wd |= (1u << 9) | ((unsigned int)addr << 11);
        if (memf)  wd |= (1u << 10);
        smask[lane] = wd;
    }
    __syncthreads();

    const int outBase = bk * (CHUNK * QPP);              // bk * 8192
    #pragma unroll 8
    for (int i = 0; i < 32; ++i) {
        int q = i * 256 + t;                             // 0..8191, coalesced
        int pos = q >> 7;
        int dq = q & 127;
        unsigned int pw = smask[pos];
        int tk = (int)(pw & 511u);
        f32x4 v = emb[tk * QPP + dq];
        unsigned int flags = pw >> 9;
        if (flags) {                                     // wave-uniform, mostly false
            bool valid = (flags & 1u) != 0u;
            bool memf  = (flags & 2u) != 0u;
            int addr = (int)(flags >> 2);
            int p0 = ADDR_KEY      + (addr & 15);
            int p1 = ADDR_KEY + 16 + ((addr >> 4) & 15);
            int p2 = ADDR_KEY + 32 + ((addr >> 8) & 15);
            int d0 = dq << 2;
            #pragma unroll
            for (int j = 0; j < 4; ++j) {
                int d = d0 + j;
                if ((valid && (d == p0 || d == p1 || d == p2)) ||
                    (memf && d == MEM_STORE)) v[j] = 1.0f;
            }
        }
        out[outBase + q] = v;                            // regular through-L2 store
    }
}

extern "C" void kernel_launch(void* const* d_in, const int* in_sizes, int n_in,
                              void* d_out, int out_size, void* d_ws, size_t ws_size,
                              hipStream_t stream) {
    const int* tok = (const int*)d_in[0];
    const f32x4* emb = (const f32x4*)d_in[1];
    const int* mhe = (const int*)d_in[2];
    int2* summ = (int2*)d_ws;             // 16*128*8 = 16 KiB
    f32x4* out = (f32x4*)d_out;

    vm_summary_kernel<<<Bb, 128, 0, stream>>>(tok, summ);
    vm_gather_kernel<<<Bb * NCH, 256, 0, stream>>>(tok, emb, summ, mhe, out);
}